// Round 1
// baseline (1264.698 us; speedup 1.0000x reference)
//
#include <hip/hip_runtime.h>

#define NN 100000
#define NE 1600000
#define NG 1024
#define D 64
#define DE 6
#define FAN 70
#define EPS 1e-5f

#define ENC_NEGINF 0x007FFFFFu

__device__ __forceinline__ unsigned enc(float f) {
    unsigned u = __float_as_uint(f);
    return (u & 0x80000000u) ? ~u : (u | 0x80000000u);
}
__device__ __forceinline__ float dec(unsigned u) {
    return (u & 0x80000000u) ? __uint_as_float(u & 0x7FFFFFFFu) : __uint_as_float(~u);
}

__global__ void k_fill_u32x4(uint4* __restrict__ p, unsigned v, int n4) {
    int i = blockIdx.x * 256 + threadIdx.x;
    if (i < n4) p[i] = make_uint4(v, v, v, v);
}

// seg-max of edge_attr by dst (computed once, reused all 3 layers)
__global__ void k_scatter_e(const float* __restrict__ ea, const int* __restrict__ dst,
                            unsigned* __restrict__ eaggk) {
    int e = blockIdx.x * 32 + (threadIdx.x >> 3);
    if (e >= NE) return;
    int t = threadIdx.x & 7;
    if (t >= DE) return;
    int d = __ldg(&dst[e]);
    unsigned k = enc(ea[e * DE + t]);
    unsigned* addr = &eaggk[d * DE + t];
    if (k > *addr) atomicMax(addr, k);
}

// seg-max of x[src] by dst: 64 lanes per edge, one dim each
__global__ void k_scatter_x(const float* __restrict__ x, const int* __restrict__ src,
                            const int* __restrict__ dst, unsigned* __restrict__ aggk) {
    int e = blockIdx.x * 4 + (threadIdx.x >> 6);
    if (e >= NE) return;
    int t = threadIdx.x & 63;
    int s = __ldg(&src[e]);
    int d = __ldg(&dst[e]);
    unsigned k = enc(x[s * D + t]);
    unsigned* addr = &aggk[d * D + t];
    if (k > *addr) atomicMax(addr, k);
}

// h = agg @ W + b  (agg = [dec(aggk) | dec(eaggk)], -inf -> 0), write h, accumulate stats
__launch_bounds__(256)
__global__ void k_gemm(const unsigned* __restrict__ aggk, const unsigned* __restrict__ eaggk,
                       const float* __restrict__ W, const float* __restrict__ b,
                       float* __restrict__ C, float* __restrict__ stats) {
    __shared__ float Wl[FAN][D];   // 17.9 KB
    __shared__ float Agx[64][D];   // 16.4 KB
    __shared__ float Age[64][8];   // 2 KB
    __shared__ float Sred[2][4][64];

    int tid = threadIdx.x;
    int n0 = blockIdx.x * 64;

    for (int i = tid; i < FAN * D; i += 256) Wl[i >> 6][i & 63] = W[i];
    for (int i = tid; i < 64 * D; i += 256) {
        int n = n0 + (i >> 6);
        unsigned u = (n < NN) ? aggk[n * D + (i & 63)] : ENC_NEGINF;
        Agx[i >> 6][i & 63] = (u == ENC_NEGINF) ? 0.f : dec(u);
    }
    for (int i = tid; i < 64 * 8; i += 256) {
        int n = n0 + (i >> 3), t = i & 7;
        float v = 0.f;
        if (t < DE && n < NN) {
            unsigned u = eaggk[n * DE + t];
            v = (u == ENC_NEGINF) ? 0.f : dec(u);
        }
        Age[i >> 3][t] = v;
    }
    __syncthreads();

    int j = tid & 63, w = tid >> 6;
    float bj = b[j];
    float psum = 0.f, psq = 0.f;
    for (int i = 0; i < 16; ++i) {
        int r = w * 16 + i;
        int n = n0 + r;
        float acc = bj;
        #pragma unroll
        for (int k = 0; k < D; ++k) acc = fmaf(Agx[r][k], Wl[k][j], acc);
        #pragma unroll
        for (int k = 0; k < DE; ++k) acc = fmaf(Age[r][k], Wl[D + k][j], acc);
        if (n < NN) {
            C[n * D + j] = acc;
            psum += acc;
            psq += acc * acc;
        }
    }
    Sred[0][w][j] = psum;
    Sred[1][w][j] = psq;
    __syncthreads();
    if (tid < 64) {
        float s = Sred[0][0][j] + Sred[0][1][j] + Sred[0][2][j] + Sred[0][3][j];
        atomicAdd(&stats[j], s);
    } else if (tid < 128) {
        float s = Sred[1][0][j] + Sred[1][1][j] + Sred[1][2][j] + Sred[1][3][j];
        atomicAdd(&stats[64 + j], s);
    }
}

__global__ void k_finalize_stats(const float* __restrict__ stats, const float* __restrict__ g,
                                 const float* __restrict__ beta, float* __restrict__ ss) {
    int j = threadIdx.x;  // 64 threads
    float mean = stats[j] * (1.0f / NN);
    float var = stats[64 + j] * (1.0f / NN) - mean * mean;
    float sc = rsqrtf(var + EPS) * g[j];
    ss[j] = sc;
    ss[64 + j] = beta[j] - mean * sc;
}

__global__ void k_norm_relu(float4* __restrict__ C, const float* __restrict__ ss, int n4) {
    int i = blockIdx.x * 256 + threadIdx.x;
    if (i >= n4) return;
    float4 v = C[i];
    int j = (i & 15) * 4;
    v.x = fmaxf(fmaf(v.x, ss[j + 0], ss[64 + j + 0]), 0.f);
    v.y = fmaxf(fmaf(v.y, ss[j + 1], ss[64 + j + 1]), 0.f);
    v.z = fmaxf(fmaf(v.z, ss[j + 2], ss[64 + j + 2]), 0.f);
    v.w = fmaxf(fmaf(v.w, ss[j + 3], ss[64 + j + 3]), 0.f);
    C[i] = v;
}

__global__ void k_pool(const float* __restrict__ C, const int* __restrict__ batch,
                       unsigned* __restrict__ poolk) {
    int n = blockIdx.x * 4 + (threadIdx.x >> 6);
    if (n >= NN) return;
    int t = threadIdx.x & 63;
    int gr = __ldg(&batch[n]);
    unsigned k = enc(C[n * D + t]);
    unsigned* addr = &poolk[gr * D + t];
    if (k > *addr) atomicMax(addr, k);
}

__global__ void k_final(const unsigned* __restrict__ poolk, const float* __restrict__ lw,
                        const float* __restrict__ lb, float* __restrict__ out) {
    int gr = blockIdx.x * 4 + (threadIdx.x >> 6);
    int j = threadIdx.x & 63;
    unsigned u = poolk[gr * D + j];
    float v = (u == ENC_NEGINF) ? 0.f : dec(u);
    float p = v * lw[j];
    #pragma unroll
    for (int off = 32; off > 0; off >>= 1) p += __shfl_down(p, off);
    if (j == 0) out[gr] = p + lb[0];
}

extern "C" void kernel_launch(void* const* d_in, const int* in_sizes, int n_in,
                              void* d_out, int out_size, void* d_ws, size_t ws_size,
                              hipStream_t stream) {
    const float* x     = (const float*)d_in[0];
    const int*   ei    = (const int*)d_in[1];
    const float* ea    = (const float*)d_in[2];
    const int*   batch = (const int*)d_in[3];
    const float* Wp[3] = {(const float*)d_in[4],  (const float*)d_in[8],  (const float*)d_in[12]};
    const float* bp[3] = {(const float*)d_in[5],  (const float*)d_in[9],  (const float*)d_in[13]};
    const float* gp[3] = {(const float*)d_in[6],  (const float*)d_in[10], (const float*)d_in[14]};
    const float* tp[3] = {(const float*)d_in[7],  (const float*)d_in[11], (const float*)d_in[15]};
    const float* lw    = (const float*)d_in[16];
    const float* lb    = (const float*)d_in[17];
    float* out = (float*)d_out;

    const int* src = ei;
    const int* dst = ei + NE;

    unsigned* aggk  = (unsigned*)d_ws;            // NN*64
    unsigned* eaggk = aggk + (size_t)NN * D;      // NN*6
    float*    C     = (float*)(eaggk + (size_t)NN * DE); // NN*64
    float*    stats = C + (size_t)NN * D;         // 128
    float*    ss    = stats + 128;                // 128
    unsigned* poolk = (unsigned*)(ss + 128);      // NG*64

    // edge_attr seg-max: once
    {
        int n4 = NN * DE / 4;
        k_fill_u32x4<<<(n4 + 255) / 256, 256, 0, stream>>>((uint4*)eaggk, ENC_NEGINF, n4);
        k_scatter_e<<<NE / 32, 256, 0, stream>>>(ea, dst, eaggk);
    }

    const float* xin = x;
    for (int l = 0; l < 3; ++l) {
        int n4 = NN * D / 4;
        k_fill_u32x4<<<(n4 + 255) / 256, 256, 0, stream>>>((uint4*)aggk, ENC_NEGINF, n4);
        k_scatter_x<<<NE / 4, 256, 0, stream>>>(xin, src, dst, aggk);
        k_fill_u32x4<<<1, 32, 0, stream>>>((uint4*)stats, 0u, 32);
        k_gemm<<<(NN + 63) / 64, 256, 0, stream>>>(aggk, eaggk, Wp[l], bp[l], C, stats);
        k_finalize_stats<<<1, 64, 0, stream>>>(stats, gp[l], tp[l], ss);
        k_norm_relu<<<(NN * 16 + 255) / 256, 256, 0, stream>>>((float4*)C, ss, NN * 16);
        xin = C;
    }

    {
        int n4 = NG * D / 4;
        k_fill_u32x4<<<(n4 + 255) / 256, 256, 0, stream>>>((uint4*)poolk, ENC_NEGINF, n4);
        k_pool<<<NN / 4, 256, 0, stream>>>(C, batch, poolk);
        k_final<<<NG / 4, 256, 0, stream>>>(poolk, lw, lb, out);
    }
}

// Round 2
// 783.374 us; speedup vs baseline: 1.6144x; 1.6144x over previous
//
#include <hip/hip_runtime.h>

#define NN 100000
#define NE 1600000
#define NG 1024
#define D 64
#define DE 6
#define FAN 70
#define EPS 1e-5f

#define ENC_NEGINF 0x007FFFFFu

__device__ __forceinline__ unsigned enc(float f) {
    unsigned u = __float_as_uint(f);
    return (u & 0x80000000u) ? ~u : (u | 0x80000000u);
}
__device__ __forceinline__ float dec(unsigned u) {
    return (u & 0x80000000u) ? __uint_as_float(u & 0x7FFFFFFFu) : __uint_as_float(~u);
}

__global__ void k_fill_u32x4(uint4* __restrict__ p, unsigned v, int n4) {
    int i = blockIdx.x * 256 + threadIdx.x;
    if (i < n4) p[i] = make_uint4(v, v, v, v);
}

// ---------------- CSR build (once per launch, reused by all 3 layers) ----------------
__global__ void k_hist(const int* __restrict__ dst, int* __restrict__ counts) {
    int e = blockIdx.x * 256 + threadIdx.x;
    if (e < NE) atomicAdd(&counts[dst[e]], 1);
}

#define SCAN_BS 512
__global__ void k_scan1(const int* __restrict__ counts, int* __restrict__ excl,
                        int* __restrict__ bsum) {
    __shared__ int s[SCAN_BS];
    int t = threadIdx.x;
    int i = blockIdx.x * SCAN_BS + t;
    int c = (i < NN) ? counts[i] : 0;
    s[t] = c;
    __syncthreads();
    for (int off = 1; off < SCAN_BS; off <<= 1) {
        int v = (t >= off) ? s[t - off] : 0;
        __syncthreads();
        s[t] += v;
        __syncthreads();
    }
    if (i < NN) excl[i] = s[t] - c;   // exclusive within block
    if (t == SCAN_BS - 1) bsum[blockIdx.x] = s[t];
}

__global__ void k_scan2(int* __restrict__ bsum, int nb) {
    __shared__ int s[256];
    int t = threadIdx.x;
    int c = (t < nb) ? bsum[t] : 0;
    s[t] = c;
    __syncthreads();
    for (int off = 1; off < 256; off <<= 1) {
        int v = (t >= off) ? s[t - off] : 0;
        __syncthreads();
        s[t] += v;
        __syncthreads();
    }
    if (t < nb) bsum[t] = s[t] - c;   // exclusive
}

__global__ void k_scan3(int* __restrict__ rowptr, const int* __restrict__ bsum,
                        int* __restrict__ cursor) {
    int i = blockIdx.x * 256 + threadIdx.x;
    if (i < NN) {
        int v = rowptr[i] + bsum[i >> 9];
        rowptr[i] = v;
        cursor[i] = v;
    }
    if (i == NN) rowptr[NN] = NE;
}

__global__ void k_fill_edges(const int* __restrict__ src, const int* __restrict__ dst,
                             int* __restrict__ cursor, int* __restrict__ esrc) {
    int e = blockIdx.x * 256 + threadIdx.x;
    if (e < NE) {
        int d = dst[e];
        int pos = atomicAdd(&cursor[d], 1);
        esrc[pos] = src[e];
    }
}

// ---------------- edge_attr seg-max (once, layer-invariant) ----------------
__global__ void k_scatter_e(const float* __restrict__ ea, const int* __restrict__ dst,
                            unsigned* __restrict__ eaggk) {
    int e = blockIdx.x * 32 + (threadIdx.x >> 3);
    if (e >= NE) return;
    int t = threadIdx.x & 7;
    if (t >= DE) return;
    int d = __ldg(&dst[e]);
    unsigned k = enc(ea[e * DE + t]);
    unsigned* addr = &eaggk[d * DE + t];
    if (k > *addr) atomicMax(addr, k);
}

// ---------------- gather-max aggregation: one wave per node ----------------
// For l>=1 applies fused norm+relu of the PREVIOUS layer post-max (valid: scale>0, monotone).
__launch_bounds__(256)
__global__ void k_aggregate(const float* __restrict__ in, const int* __restrict__ rowptr,
                            const int* __restrict__ esrc, const float* __restrict__ ss,
                            float* __restrict__ agg, int apply) {
    int n = blockIdx.x * 4 + (threadIdx.x >> 6);
    int t = threadIdx.x & 63;
    int rs = rowptr[n], re = rowptr[n + 1];
    float m = -__builtin_inff();
    int j = rs;
    for (; j + 4 <= re; j += 4) {
        int s0 = esrc[j], s1 = esrc[j + 1], s2 = esrc[j + 2], s3 = esrc[j + 3];
        float v0 = in[(size_t)s0 * D + t];
        float v1 = in[(size_t)s1 * D + t];
        float v2 = in[(size_t)s2 * D + t];
        float v3 = in[(size_t)s3 * D + t];
        m = fmaxf(fmaxf(m, fmaxf(v0, v1)), fmaxf(v2, v3));
    }
    for (; j < re; ++j) m = fmaxf(m, in[(size_t)esrc[j] * D + t]);
    float out;
    if (re == rs) out = 0.f;
    else if (apply) out = fmaxf(fmaf(m, ss[t], ss[D + t]), 0.f);
    else out = m;
    agg[(size_t)n * D + t] = out;
}

// ---------------- h = [agg | eagg] @ W + b, with per-feature sum/sumsq ----------------
__launch_bounds__(256)
__global__ void k_gemm(const float* __restrict__ agg, const unsigned* __restrict__ eaggk,
                       const float* __restrict__ W, const float* __restrict__ b,
                       float* __restrict__ C, float* __restrict__ stats) {
    __shared__ float Wl[FAN][D];    // 17.9 KB
    __shared__ float Ag[64][73];    // 18.7 KB (stride 73: kills 288%32==0 bank alias)
    __shared__ float ls[128];

    int tid = threadIdx.x;
    int n0 = blockIdx.x * 64;

    for (int i = tid; i < FAN * D; i += 256) Wl[i >> 6][i & 63] = W[i];
    for (int i = tid; i < 64 * 64; i += 256) {
        int r = i >> 6, c = i & 63;
        int n = n0 + r;
        Ag[r][c] = (n < NN) ? agg[(size_t)n * D + c] : 0.f;
    }
    for (int i = tid; i < 64 * 8; i += 256) {
        int r = i >> 3, c = i & 7;
        int n = n0 + r;
        float v = 0.f;
        if (c < DE && n < NN) {
            unsigned u = eaggk[n * DE + c];
            v = (u == ENC_NEGINF) ? 0.f : dec(u);
        }
        if (c < 8) Ag[r][64 + c] = v;   // cols 70..71 padding stay 0, never read
    }
    if (tid < 128) ls[tid] = 0.f;
    __syncthreads();

    int tr = tid >> 4, tc = tid & 15;
    int r0 = tr * 4, c0 = tc * 4;
    float acc[4][4];
    #pragma unroll
    for (int i = 0; i < 4; i++)
        #pragma unroll
        for (int jj = 0; jj < 4; jj++) acc[i][jj] = 0.f;

    for (int k = 0; k < FAN; k++) {
        float4 wv = *(const float4*)&Wl[k][c0];
        float a0 = Ag[r0 + 0][k];
        float a1 = Ag[r0 + 1][k];
        float a2 = Ag[r0 + 2][k];
        float a3 = Ag[r0 + 3][k];
        acc[0][0] = fmaf(a0, wv.x, acc[0][0]); acc[0][1] = fmaf(a0, wv.y, acc[0][1]);
        acc[0][2] = fmaf(a0, wv.z, acc[0][2]); acc[0][3] = fmaf(a0, wv.w, acc[0][3]);
        acc[1][0] = fmaf(a1, wv.x, acc[1][0]); acc[1][1] = fmaf(a1, wv.y, acc[1][1]);
        acc[1][2] = fmaf(a1, wv.z, acc[1][2]); acc[1][3] = fmaf(a1, wv.w, acc[1][3]);
        acc[2][0] = fmaf(a2, wv.x, acc[2][0]); acc[2][1] = fmaf(a2, wv.y, acc[2][1]);
        acc[2][2] = fmaf(a2, wv.z, acc[2][2]); acc[2][3] = fmaf(a2, wv.w, acc[2][3]);
        acc[3][0] = fmaf(a3, wv.x, acc[3][0]); acc[3][1] = fmaf(a3, wv.y, acc[3][1]);
        acc[3][2] = fmaf(a3, wv.z, acc[3][2]); acc[3][3] = fmaf(a3, wv.w, acc[3][3]);
    }

    float4 bb = *(const float4*)&b[c0];
    float cs[4] = {0.f, 0.f, 0.f, 0.f};
    float cq[4] = {0.f, 0.f, 0.f, 0.f};
    #pragma unroll
    for (int i = 0; i < 4; i++) {
        int n = n0 + r0 + i;
        if (n < NN) {
            float4 o;
            o.x = acc[i][0] + bb.x; o.y = acc[i][1] + bb.y;
            o.z = acc[i][2] + bb.z; o.w = acc[i][3] + bb.w;
            *(float4*)&C[(size_t)n * D + c0] = o;
            cs[0] += o.x; cs[1] += o.y; cs[2] += o.z; cs[3] += o.w;
            cq[0] += o.x * o.x; cq[1] += o.y * o.y; cq[2] += o.z * o.z; cq[3] += o.w * o.w;
        }
    }
    #pragma unroll
    for (int jj = 0; jj < 4; jj++) {
        atomicAdd(&ls[c0 + jj], cs[jj]);
        atomicAdd(&ls[64 + c0 + jj], cq[jj]);
    }
    __syncthreads();
    if (tid < 128) atomicAdd(&stats[tid], ls[tid]);
}

__global__ void k_finalize_stats(const float* __restrict__ stats, const float* __restrict__ g,
                                 const float* __restrict__ beta, float* __restrict__ ss) {
    int j = threadIdx.x;  // 64 threads
    float mean = stats[j] * (1.0f / NN);
    float var = stats[64 + j] * (1.0f / NN) - mean * mean;
    float sc = rsqrtf(var + EPS) * g[j];
    ss[j] = sc;
    ss[64 + j] = beta[j] - mean * sc;
}

// pool raw h2 (norm+relu applied post-pool in k_final; valid since scale>0, monotone)
__global__ void k_pool(const float* __restrict__ C, const int* __restrict__ batch,
                       unsigned* __restrict__ poolk) {
    int n = blockIdx.x * 4 + (threadIdx.x >> 6);
    if (n >= NN) return;
    int t = threadIdx.x & 63;
    int gr = __ldg(&batch[n]);
    unsigned k = enc(C[n * D + t]);
    unsigned* addr = &poolk[gr * D + t];
    if (k > *addr) atomicMax(addr, k);
}

__global__ void k_final(const unsigned* __restrict__ poolk, const float* __restrict__ ss,
                        const float* __restrict__ lw, const float* __restrict__ lb,
                        float* __restrict__ out) {
    int gr = blockIdx.x * 4 + (threadIdx.x >> 6);
    int j = threadIdx.x & 63;
    unsigned u = poolk[gr * D + j];
    float v = (u == ENC_NEGINF) ? 0.f : fmaxf(fmaf(dec(u), ss[j], ss[D + j]), 0.f);
    float p = v * lw[j];
    #pragma unroll
    for (int off = 32; off > 0; off >>= 1) p += __shfl_down(p, off);
    if (j == 0) out[gr] = p + lb[0];
}

extern "C" void kernel_launch(void* const* d_in, const int* in_sizes, int n_in,
                              void* d_out, int out_size, void* d_ws, size_t ws_size,
                              hipStream_t stream) {
    const float* x     = (const float*)d_in[0];
    const int*   ei    = (const int*)d_in[1];
    const float* ea    = (const float*)d_in[2];
    const int*   batch = (const int*)d_in[3];
    const float* Wp[3] = {(const float*)d_in[4],  (const float*)d_in[8],  (const float*)d_in[12]};
    const float* bp[3] = {(const float*)d_in[5],  (const float*)d_in[9],  (const float*)d_in[13]};
    const float* gp[3] = {(const float*)d_in[6],  (const float*)d_in[10], (const float*)d_in[14]};
    const float* tp[3] = {(const float*)d_in[7],  (const float*)d_in[11], (const float*)d_in[15]};
    const float* lw    = (const float*)d_in[16];
    const float* lb    = (const float*)d_in[17];
    float* out = (float*)d_out;

    const int* src = ei;
    const int* dst = ei + NE;

    // workspace layout (4-byte words, all 16B-aligned)
    unsigned* w = (unsigned*)d_ws;
    int*      rowptr = (int*)w;                    // 100004 words
    int*      cursor = (int*)(w + 100004);         // 100000 (aliases counts)
    int*      esrc   = (int*)(w + 200004);         // 1600000
    unsigned* eaggk  = w + 1800004;                // 600000
    int*      bsum   = (int*)(w + 2400004);        // 256
    float*    stats  = (float*)(w + 2400260);      // 128
    float*    ss     = (float*)(w + 2400388);      // 128
    unsigned* poolk  = w + 2400516;                // 65536
    float*    A      = (float*)(w + 2466052);      // 6400000
    float*    H      = (float*)(w + 8866052);      // 6400000

    const int NB = (NN + SCAN_BS - 1) / SCAN_BS;   // 196

    // --- CSR build (counts aliases cursor) ---
    k_fill_u32x4<<<(25000 + 255) / 256, 256, 0, stream>>>((uint4*)cursor, 0u, 25000);
    k_hist<<<NE / 256, 256, 0, stream>>>(dst, cursor);
    k_scan1<<<NB, SCAN_BS, 0, stream>>>(cursor, rowptr, bsum);
    k_scan2<<<1, 256, 0, stream>>>(bsum, NB);
    k_scan3<<<(NN + 1 + 255) / 256, 256, 0, stream>>>(rowptr, bsum, cursor);
    k_fill_edges<<<NE / 256, 256, 0, stream>>>(src, dst, cursor, esrc);

    // --- edge_attr seg-max once ---
    k_fill_u32x4<<<(150000 + 255) / 256, 256, 0, stream>>>((uint4*)eaggk, ENC_NEGINF, 150000);
    k_scatter_e<<<NE / 32, 256, 0, stream>>>(ea, dst, eaggk);

    // --- 3 layers ---
    const float* xin = x;
    for (int l = 0; l < 3; ++l) {
        k_aggregate<<<NN / 4, 256, 0, stream>>>(xin, rowptr, esrc, ss, A, l > 0 ? 1 : 0);
        k_fill_u32x4<<<1, 32, 0, stream>>>((uint4*)stats, 0u, 32);
        k_gemm<<<(NN + 63) / 64, 256, 0, stream>>>(A, eaggk, Wp[l], bp[l], H, stats);
        k_finalize_stats<<<1, 64, 0, stream>>>(stats, gp[l], tp[l], ss);
        xin = H;
    }

    // --- pool raw h2 + final transform/dot ---
    k_fill_u32x4<<<(16384 + 255) / 256, 256, 0, stream>>>((uint4*)poolk, ENC_NEGINF, 16384);
    k_pool<<<NN / 4, 256, 0, stream>>>(H, batch, poolk);
    k_final<<<NG / 4, 256, 0, stream>>>(poolk, ss, lw, lb, out);
}

// Round 3
// 742.654 us; speedup vs baseline: 1.7029x; 1.0548x over previous
//
#include <hip/hip_runtime.h>

#define NN 100000
#define NE 1600000
#define NG 1024
#define D 64
#define DE 6
#define FAN 70
#define EPS 1e-5f

#define ENC_NEGINF 0x007FFFFFu
#define NINF (-__builtin_inff())

__device__ __forceinline__ unsigned enc(float f) {
    unsigned u = __float_as_uint(f);
    return (u & 0x80000000u) ? ~u : (u | 0x80000000u);
}
__device__ __forceinline__ float dec(unsigned u) {
    return (u & 0x80000000u) ? __uint_as_float(u & 0x7FFFFFFFu) : __uint_as_float(~u);
}
__device__ __forceinline__ unsigned bfr(float f) {   // fp32 -> bf16 bits, RNE
    unsigned u = __float_as_uint(f);
    return (u + 0x7FFFu + ((u >> 16) & 1)) >> 16;
}
__device__ __forceinline__ float blo(unsigned w) { return __uint_as_float(w << 16); }
__device__ __forceinline__ float bhi(unsigned w) { return __uint_as_float(w & 0xFFFF0000u); }

__global__ void k_fill_u32x4(uint4* __restrict__ p, unsigned v, int n4) {
    int i = blockIdx.x * 256 + threadIdx.x;
    if (i < n4) p[i] = make_uint4(v, v, v, v);
}

// fp32 row-major [NN][64] -> bf16-packed [NN][32] u32
__global__ void k_cast(const float4* __restrict__ in, uint2* __restrict__ out, int n4) {
    int i = blockIdx.x * 256 + threadIdx.x;
    if (i < n4) {
        float4 v = in[i];
        out[i] = make_uint2(bfr(v.x) | (bfr(v.y) << 16), bfr(v.z) | (bfr(v.w) << 16));
    }
}

// ---------------- CSR build ----------------
__global__ void k_hist(const int* __restrict__ dst, int* __restrict__ counts) {
    int e = blockIdx.x * 256 + threadIdx.x;
    if (e < NE) atomicAdd(&counts[dst[e]], 1);
}

#define SCAN_BS 512
__global__ void k_scan1(const int* __restrict__ counts, int* __restrict__ excl,
                        int* __restrict__ bsum) {
    __shared__ int s[SCAN_BS];
    int t = threadIdx.x;
    int i = blockIdx.x * SCAN_BS + t;
    int c = (i < NN) ? counts[i] : 0;
    s[t] = c;
    __syncthreads();
    for (int off = 1; off < SCAN_BS; off <<= 1) {
        int v = (t >= off) ? s[t - off] : 0;
        __syncthreads();
        s[t] += v;
        __syncthreads();
    }
    if (i < NN) excl[i] = s[t] - c;
    if (t == SCAN_BS - 1) bsum[blockIdx.x] = s[t];
}

__global__ void k_scan2(int* __restrict__ bsum, int nb) {
    __shared__ int s[256];
    int t = threadIdx.x;
    int c = (t < nb) ? bsum[t] : 0;
    s[t] = c;
    __syncthreads();
    for (int off = 1; off < 256; off <<= 1) {
        int v = (t >= off) ? s[t - off] : 0;
        __syncthreads();
        s[t] += v;
        __syncthreads();
    }
    if (t < nb) bsum[t] = s[t] - c;
}

__global__ void k_scan3(int* __restrict__ rowptr, const int* __restrict__ bsum,
                        int* __restrict__ cursor) {
    int i = blockIdx.x * 256 + threadIdx.x;
    if (i < NN) {
        int v = rowptr[i] + bsum[i >> 9];
        rowptr[i] = v;
        cursor[i] = v;
    }
    if (i == NN) rowptr[NN] = NE;
}

__global__ void k_fill_edges(const int* __restrict__ src, const int* __restrict__ dst,
                             int* __restrict__ cursor, int* __restrict__ esrc) {
    int e = blockIdx.x * 256 + threadIdx.x;
    if (e < NE) {
        int d = dst[e];
        int pos = atomicAdd(&cursor[d], 1);
        esrc[pos] = src[e];
    }
}

// ---------------- edge_attr seg-max (layer-invariant) ----------------
__global__ void k_scatter_e(const float* __restrict__ ea, const int* __restrict__ dst,
                            unsigned* __restrict__ eaggk) {
    int e = blockIdx.x * 32 + (threadIdx.x >> 3);
    if (e >= NE) return;
    int t = threadIdx.x & 7;
    if (t >= DE) return;
    int d = __ldg(&dst[e]);
    unsigned k = enc(ea[e * DE + t]);
    unsigned* addr = &eaggk[d * DE + t];
    if (k > *addr) atomicMax(addr, k);
}

// ---------------- fused layer: gather-max (+prev norm/relu) + GEMM + stats ----------------
// Xb: bf16-packed input rows [NN][32] u32. Hb: bf16-packed output. 64 nodes/block.
__launch_bounds__(256)
__global__ void k_layer(const unsigned* __restrict__ Xb, const int* __restrict__ rowptr,
                        const int* __restrict__ esrc, const unsigned* __restrict__ eaggk,
                        const float* __restrict__ ss, int apply,
                        const float* __restrict__ W, const float* __restrict__ b,
                        unsigned* __restrict__ Hb, float* __restrict__ stats) {
    __shared__ float Wl[FAN][D];    // 17.9 KB
    __shared__ float Ag[64][74];    // 18.9 KB (74: even for float2, group offset 296%128B -> no conflict)
    __shared__ float ls[128];

    int tid = threadIdx.x;
    int n0 = blockIdx.x * 64;

    for (int i = tid; i < FAN * D; i += 256) Wl[i >> 6][i & 63] = W[i];
    for (int i = tid; i < 64 * 6; i += 256) {
        int r = i / 6, c = i % 6;
        int n = n0 + r;
        float v = 0.f;
        if (n < NN) {
            unsigned u = eaggk[n * DE + c];
            v = (u == ENC_NEGINF) ? 0.f : dec(u);
        }
        Ag[r][64 + c] = v;
    }
    if (tid < 128) ls[tid] = 0.f;

    // gather phase: wave w handles 16 nodes as 8 half-wave pairs; lane covers dims 2lt,2lt+1
    int w = tid >> 6, lane = tid & 63, half = lane >> 5, lt = lane & 31;
    float s0 = 0.f, h0 = 0.f, s1 = 0.f, h1 = 0.f;
    if (apply) {
        s0 = ss[2 * lt];     h0 = ss[D + 2 * lt];
        s1 = ss[2 * lt + 1]; h1 = ss[D + 2 * lt + 1];
    }
    #pragma unroll 2
    for (int p = 0; p < 8; ++p) {
        int node = n0 + w * 16 + 2 * p + half;
        float a0 = 0.f, a1 = 0.f;
        if (node < NN) {
            int rs = rowptr[node], re = rowptr[node + 1];
            if (re > rs) {
                float m0 = NINF, m1 = NINF, p0 = NINF, p1 = NINF;
                int j = rs;
                for (; j + 4 <= re; j += 4) {
                    int sA = esrc[j], sB = esrc[j + 1], sC = esrc[j + 2], sD = esrc[j + 3];
                    unsigned vA = Xb[(size_t)sA * 32 + lt];
                    unsigned vB = Xb[(size_t)sB * 32 + lt];
                    unsigned vC = Xb[(size_t)sC * 32 + lt];
                    unsigned vD = Xb[(size_t)sD * 32 + lt];
                    m0 = fmaxf(m0, fmaxf(blo(vA), blo(vB)));
                    m1 = fmaxf(m1, fmaxf(bhi(vA), bhi(vB)));
                    p0 = fmaxf(p0, fmaxf(blo(vC), blo(vD)));
                    p1 = fmaxf(p1, fmaxf(bhi(vC), bhi(vD)));
                }
                for (; j < re; ++j) {
                    unsigned v = Xb[(size_t)esrc[j] * 32 + lt];
                    m0 = fmaxf(m0, blo(v));
                    m1 = fmaxf(m1, bhi(v));
                }
                m0 = fmaxf(m0, p0);
                m1 = fmaxf(m1, p1);
                if (apply) {
                    a0 = fmaxf(fmaf(m0, s0, h0), 0.f);
                    a1 = fmaxf(fmaf(m1, s1, h1), 0.f);
                } else {
                    a0 = m0;
                    a1 = m1;
                }
            }
        }
        int r = w * 16 + 2 * p + half;
        *(float2*)&Ag[r][2 * lt] = make_float2(a0, a1);
    }
    __syncthreads();

    // GEMM phase: 4x4 register tile
    int tr = tid >> 4, tc = tid & 15;
    int r0 = tr * 4, c0 = tc * 4;
    float acc[4][4];
    #pragma unroll
    for (int i = 0; i < 4; i++)
        #pragma unroll
        for (int jj = 0; jj < 4; jj++) acc[i][jj] = 0.f;

    for (int k = 0; k < FAN; k++) {
        float4 wv = *(const float4*)&Wl[k][c0];
        float a0 = Ag[r0 + 0][k];
        float a1 = Ag[r0 + 1][k];
        float a2 = Ag[r0 + 2][k];
        float a3 = Ag[r0 + 3][k];
        acc[0][0] = fmaf(a0, wv.x, acc[0][0]); acc[0][1] = fmaf(a0, wv.y, acc[0][1]);
        acc[0][2] = fmaf(a0, wv.z, acc[0][2]); acc[0][3] = fmaf(a0, wv.w, acc[0][3]);
        acc[1][0] = fmaf(a1, wv.x, acc[1][0]); acc[1][1] = fmaf(a1, wv.y, acc[1][1]);
        acc[1][2] = fmaf(a1, wv.z, acc[1][2]); acc[1][3] = fmaf(a1, wv.w, acc[1][3]);
        acc[2][0] = fmaf(a2, wv.x, acc[2][0]); acc[2][1] = fmaf(a2, wv.y, acc[2][1]);
        acc[2][2] = fmaf(a2, wv.z, acc[2][2]); acc[2][3] = fmaf(a2, wv.w, acc[2][3]);
        acc[3][0] = fmaf(a3, wv.x, acc[3][0]); acc[3][1] = fmaf(a3, wv.y, acc[3][1]);
        acc[3][2] = fmaf(a3, wv.z, acc[3][2]); acc[3][3] = fmaf(a3, wv.w, acc[3][3]);
    }

    float4 bb = *(const float4*)&b[c0];
    float cs[4] = {0.f, 0.f, 0.f, 0.f};
    float cq[4] = {0.f, 0.f, 0.f, 0.f};
    #pragma unroll
    for (int i = 0; i < 4; i++) {
        int n = n0 + r0 + i;
        if (n < NN) {
            float ox = acc[i][0] + bb.x, oy = acc[i][1] + bb.y;
            float oz = acc[i][2] + bb.z, ow = acc[i][3] + bb.w;
            uint2 pk = make_uint2(bfr(ox) | (bfr(oy) << 16), bfr(oz) | (bfr(ow) << 16));
            *(uint2*)&Hb[(size_t)n * 32 + (c0 >> 1)] = pk;
            cs[0] += ox; cs[1] += oy; cs[2] += oz; cs[3] += ow;
            cq[0] += ox * ox; cq[1] += oy * oy; cq[2] += oz * oz; cq[3] += ow * ow;
        }
    }
    #pragma unroll
    for (int jj = 0; jj < 4; jj++) {
        atomicAdd(&ls[c0 + jj], cs[jj]);
        atomicAdd(&ls[64 + c0 + jj], cq[jj]);
    }
    __syncthreads();
    if (tid < 128) atomicAdd(&stats[tid], ls[tid]);
}

__global__ void k_finalize_stats(const float* __restrict__ stats, const float* __restrict__ g,
                                 const float* __restrict__ beta, float* __restrict__ ss) {
    int j = threadIdx.x;  // 64 threads
    float mean = stats[j] * (1.0f / NN);
    float var = stats[64 + j] * (1.0f / NN) - mean * mean;
    float sc = rsqrtf(var + EPS) * g[j];
    ss[j] = sc;
    ss[64 + j] = beta[j] - mean * sc;
}

// pool raw bf16 h2 (norm+relu post-pool in k_final; monotone)
__global__ void k_pool(const unsigned* __restrict__ Hb, const int* __restrict__ batch,
                       unsigned* __restrict__ poolk) {
    int n = blockIdx.x * 4 + (threadIdx.x >> 6);
    if (n >= NN) return;
    int t = threadIdx.x & 63;
    int gr = __ldg(&batch[n]);
    unsigned wv = Hb[(size_t)n * 32 + (t >> 1)];
    float v = (t & 1) ? bhi(wv) : blo(wv);
    unsigned k = enc(v);
    unsigned* addr = &poolk[gr * D + t];
    if (k > *addr) atomicMax(addr, k);
}

__global__ void k_final(const unsigned* __restrict__ poolk, const float* __restrict__ ss,
                        const float* __restrict__ lw, const float* __restrict__ lb,
                        float* __restrict__ out) {
    int gr = blockIdx.x * 4 + (threadIdx.x >> 6);
    int j = threadIdx.x & 63;
    unsigned u = poolk[gr * D + j];
    float v = (u == ENC_NEGINF) ? 0.f : fmaxf(fmaf(dec(u), ss[j], ss[D + j]), 0.f);
    float p = v * lw[j];
    #pragma unroll
    for (int off = 32; off > 0; off >>= 1) p += __shfl_down(p, off);
    if (j == 0) out[gr] = p + lb[0];
}

extern "C" void kernel_launch(void* const* d_in, const int* in_sizes, int n_in,
                              void* d_out, int out_size, void* d_ws, size_t ws_size,
                              hipStream_t stream) {
    const float* x     = (const float*)d_in[0];
    const int*   ei    = (const int*)d_in[1];
    const float* ea    = (const float*)d_in[2];
    const int*   batch = (const int*)d_in[3];
    const float* Wp[3] = {(const float*)d_in[4],  (const float*)d_in[8],  (const float*)d_in[12]};
    const float* bp[3] = {(const float*)d_in[5],  (const float*)d_in[9],  (const float*)d_in[13]};
    const float* gp[3] = {(const float*)d_in[6],  (const float*)d_in[10], (const float*)d_in[14]};
    const float* tp[3] = {(const float*)d_in[7],  (const float*)d_in[11], (const float*)d_in[15]};
    const float* lw    = (const float*)d_in[16];
    const float* lb    = (const float*)d_in[17];
    float* out = (float*)d_out;

    const int* src = ei;
    const int* dst = ei + NE;

    // workspace layout (u32 words; all fill targets 16B-aligned)
    unsigned* w = (unsigned*)d_ws;
    int*      rowptr = (int*)w;                    // 100004
    int*      cursor = (int*)(w + 100004);         // 100004 (aliases counts)
    int*      esrc   = (int*)(w + 200008);         // 1600000
    unsigned* eaggk  = w + 1800008;                // 600000
    int*      bsum   = (int*)(w + 2400008);        // 256
    float*    stats  = (float*)(w + 2400264);      // 128
    float*    ss     = (float*)(w + 2400392);      // 128
    unsigned* poolk  = w + 2400520;                // 65536
    unsigned* Xb0    = w + 2466056;                // 3200000 (bf16 x)
    unsigned* Hb1    = w + 5666056;                // 3200000
    unsigned* Hb2    = w + 8866056;                // 3200000

    const int NB = (NN + SCAN_BS - 1) / SCAN_BS;   // 196

    // --- CSR build (counts aliases cursor) ---
    k_fill_u32x4<<<(25001 + 255) / 256, 256, 0, stream>>>((uint4*)cursor, 0u, 25001);
    k_hist<<<NE / 256, 256, 0, stream>>>(dst, cursor);
    k_scan1<<<NB, SCAN_BS, 0, stream>>>(cursor, rowptr, bsum);
    k_scan2<<<1, 256, 0, stream>>>(bsum, NB);
    k_scan3<<<(NN + 1 + 255) / 256, 256, 0, stream>>>(rowptr, bsum, cursor);
    k_fill_edges<<<NE / 256, 256, 0, stream>>>(src, dst, cursor, esrc);

    // --- edge_attr seg-max + bf16 cast of x (independent of CSR) ---
    k_fill_u32x4<<<(150000 + 255) / 256, 256, 0, stream>>>((uint4*)eaggk, ENC_NEGINF, 150000);
    k_scatter_e<<<NE / 32, 256, 0, stream>>>(ea, dst, eaggk);
    k_cast<<<(NN * 16 + 255) / 256, 256, 0, stream>>>((const float4*)x, (uint2*)Xb0, NN * 16);

    // --- 3 fused layers (ping-pong bf16 H) ---
    const unsigned* xin = Xb0;
    unsigned* hout[3] = {Hb1, Hb2, Hb1};
    for (int l = 0; l < 3; ++l) {
        k_fill_u32x4<<<1, 32, 0, stream>>>((uint4*)stats, 0u, 32);
        k_layer<<<(NN + 63) / 64, 256, 0, stream>>>(xin, rowptr, esrc, eaggk, ss, l > 0 ? 1 : 0,
                                                    Wp[l], bp[l], hout[l], stats);
        k_finalize_stats<<<1, 64, 0, stream>>>(stats, gp[l], tp[l], ss);
        xin = hout[l];
    }

    // --- pool raw h2 + final norm/relu/dot ---
    k_fill_u32x4<<<(16384 + 255) / 256, 256, 0, stream>>>((uint4*)poolk, ENC_NEGINF, 16384);
    k_pool<<<NN / 4, 256, 0, stream>>>(Hb1, batch, poolk);
    k_final<<<NG / 4, 256, 0, stream>>>(poolk, ss, lw, lb, out);
}

// Round 4
// 718.620 us; speedup vs baseline: 1.7599x; 1.0334x over previous
//
#include <hip/hip_runtime.h>

#define NN 100000
#define NE 1600000
#define NG 1024
#define D 64
#define DE 6
#define FAN 70
#define EPS 1e-5f

#define ENC_NEGINF 0x007FFFFFu
#define NINF (-__builtin_inff())

#define NBUK 196      // dst buckets of 512 nodes
#define ACAP 96       // LDS stage capacity per bucket per binA block
#define GCAP 10240    // global per-bucket capacity (mean 8163, +20 sigma)
#define BCAP 10240    // binB LDS esrc capacity (mean 8192)

__device__ __forceinline__ unsigned enc(float f) {
    unsigned u = __float_as_uint(f);
    return (u & 0x80000000u) ? ~u : (u | 0x80000000u);
}
__device__ __forceinline__ float dec(unsigned u) {
    return (u & 0x80000000u) ? __uint_as_float(u & 0x7FFFFFFFu) : __uint_as_float(~u);
}
__device__ __forceinline__ unsigned bfr(float f) {   // fp32 -> bf16 bits, RNE
    unsigned u = __float_as_uint(f);
    return (u + 0x7FFFu + ((u >> 16) & 1)) >> 16;
}
__device__ __forceinline__ float blo(unsigned w) { return __uint_as_float(w << 16); }
__device__ __forceinline__ float bhi(unsigned w) { return __uint_as_float(w & 0xFFFF0000u); }

__global__ void k_fill_u32x4(uint4* __restrict__ p, unsigned v, int n4) {
    int i = blockIdx.x * 256 + threadIdx.x;
    if (i < n4) p[i] = make_uint4(v, v, v, v);
}

// fp32 [NN][64] -> bf16-packed [NN][32] u32
__global__ void k_cast(const float4* __restrict__ in, uint2* __restrict__ out, int n4) {
    int i = blockIdx.x * 256 + threadIdx.x;
    if (i < n4) {
        float4 v = in[i];
        out[i] = make_uint2(bfr(v.x) | (bfr(v.y) << 16), bfr(v.z) | (bfr(v.w) << 16));
    }
}

// ---------------- CSR build ----------------
__global__ void k_hist(const int* __restrict__ dst, int* __restrict__ counts) {
    int e = blockIdx.x * 256 + threadIdx.x;
    if (e < NE) atomicAdd(&counts[dst[e]], 1);
}

#define SCAN_BS 512
__global__ void k_scan1(const int* __restrict__ counts, int* __restrict__ excl,
                        int* __restrict__ bsum) {
    __shared__ int s[SCAN_BS];
    int t = threadIdx.x;
    int i = blockIdx.x * SCAN_BS + t;
    int c = (i < NN) ? counts[i] : 0;
    s[t] = c;
    __syncthreads();
    for (int off = 1; off < SCAN_BS; off <<= 1) {
        int v = (t >= off) ? s[t - off] : 0;
        __syncthreads();
        s[t] += v;
        __syncthreads();
    }
    if (i < NN) excl[i] = s[t] - c;
    if (t == SCAN_BS - 1) bsum[blockIdx.x] = s[t];
}

__global__ void k_scan2(int* __restrict__ bsum, int nb) {
    __shared__ int s[256];
    int t = threadIdx.x;
    int c = (t < nb) ? bsum[t] : 0;
    s[t] = c;
    __syncthreads();
    for (int off = 1; off < 256; off <<= 1) {
        int v = (t >= off) ? s[t - off] : 0;
        __syncthreads();
        s[t] += v;
        __syncthreads();
    }
    if (t < nb) bsum[t] = s[t] - c;
}

__global__ void k_scan3(int* __restrict__ rowptr, const int* __restrict__ bsum) {
    int i = blockIdx.x * 256 + threadIdx.x;
    if (i < NN) rowptr[i] += bsum[i >> 9];
    if (i == NN) rowptr[NN] = NE;
}

// pass A: bin edges by dst>>9 with LDS staging, coalesced bucket flushes
__launch_bounds__(256)
__global__ void k_binA(const int* __restrict__ src, const int* __restrict__ dst,
                       int* __restrict__ gcnt, unsigned* __restrict__ gbuck) {
    __shared__ unsigned stage[NBUK][ACAP];   // 75.3 KB
    __shared__ int cnt[NBUK];
    int tid = threadIdx.x;
    for (int i = tid; i < NBUK; i += 256) cnt[i] = 0;
    __syncthreads();
    int e0 = blockIdx.x * 8164;
    int e1 = min(e0 + 8164, NE);
    for (int e = e0 + tid; e < e1; e += 256) {
        int d = dst[e];
        int s = src[e];
        int b = d >> 9;
        unsigned ent = ((unsigned)s << 9) | (unsigned)(d & 511);
        int pos = atomicAdd(&cnt[b], 1);
        if (pos < ACAP) stage[b][pos] = ent;
        else {  // rare spill: direct (uncoalesced) append
            int gp = atomicAdd(&gcnt[b], 1);
            gbuck[(size_t)b * GCAP + gp] = ent;
        }
    }
    __syncthreads();
    int wv = tid >> 6, ln = tid & 63;
    for (int b = wv; b < NBUK; b += 4) {
        int c = min(cnt[b], ACAP);
        int base = 0;
        if (ln == 0 && c > 0) base = atomicAdd(&gcnt[b], c);
        base = __shfl(base, 0, 64);
        for (int i = ln; i < c; i += 64) gbuck[(size_t)b * GCAP + base + i] = stage[b][i];
    }
}

// pass B: one block per bucket; LDS scatter then coalesced stream-out
__launch_bounds__(256)
__global__ void k_binB(const unsigned* __restrict__ gbuck, const int* __restrict__ gcnt,
                       const int* __restrict__ rowptr, int* __restrict__ esrc) {
    __shared__ int curs[512];
    __shared__ unsigned el[BCAP];            // 40 KB
    int k = blockIdx.x;
    int tid = threadIdx.x;
    int nb = k << 9;
    int nend = min(nb + 512, NN);
    int rowbase = rowptr[nb];
    int regsz = rowptr[nend] - rowbase;
    for (int i = tid; i < 512; i += 256)
        curs[i] = (nb + i < nend) ? rowptr[nb + i] - rowbase : 0;
    __syncthreads();
    int total = gcnt[k];
    if (regsz <= BCAP) {
        for (int i = tid; i < total; i += 256) {
            unsigned ent = gbuck[(size_t)k * GCAP + i];
            int pos = atomicAdd(&curs[ent & 511], 1);
            el[pos] = ent >> 9;
        }
        __syncthreads();
        for (int i = tid; i < regsz; i += 256) esrc[rowbase + i] = (int)el[i];
    } else {  // capacity fallback: direct global scatter (correct, slower)
        for (int i = tid; i < total; i += 256) {
            unsigned ent = gbuck[(size_t)k * GCAP + i];
            int pos = atomicAdd(&curs[ent & 511], 1);
            esrc[rowbase + pos] = (int)(ent >> 9);
        }
    }
}

// ---------------- edge_attr seg-max (layer-invariant) ----------------
__global__ void k_scatter_e(const float* __restrict__ ea, const int* __restrict__ dst,
                            unsigned* __restrict__ eaggk) {
    int e = blockIdx.x * 32 + (threadIdx.x >> 3);
    if (e >= NE) return;
    int t = threadIdx.x & 7;
    if (t >= DE) return;
    int d = __ldg(&dst[e]);
    unsigned k = enc(ea[e * DE + t]);
    unsigned* addr = &eaggk[d * DE + t];
    if (k > *addr) atomicMax(addr, k);
}

// ---------------- gather-max: half-wave per node, raw bf16 maxima out ----------------
__global__ void k_agg(const unsigned* __restrict__ Xb, const int* __restrict__ rowptr,
                      const int* __restrict__ esrc, unsigned* __restrict__ Ab) {
    int n = blockIdx.x * 8 + (threadIdx.x >> 5);
    int lt = threadIdx.x & 31;
    if (n >= NN) return;
    int rs = rowptr[n], re = rowptr[n + 1];
    float m0 = NINF, m1 = NINF, p0 = NINF, p1 = NINF;
    int j = rs;
    for (; j + 8 <= re; j += 8) {
        int s0 = esrc[j], s1 = esrc[j + 1], s2 = esrc[j + 2], s3 = esrc[j + 3];
        int s4 = esrc[j + 4], s5 = esrc[j + 5], s6 = esrc[j + 6], s7 = esrc[j + 7];
        unsigned v0 = Xb[(size_t)s0 * 32 + lt], v1 = Xb[(size_t)s1 * 32 + lt];
        unsigned v2 = Xb[(size_t)s2 * 32 + lt], v3 = Xb[(size_t)s3 * 32 + lt];
        unsigned v4 = Xb[(size_t)s4 * 32 + lt], v5 = Xb[(size_t)s5 * 32 + lt];
        unsigned v6 = Xb[(size_t)s6 * 32 + lt], v7 = Xb[(size_t)s7 * 32 + lt];
        m0 = fmaxf(m0, fmaxf(fmaxf(blo(v0), blo(v1)), fmaxf(blo(v2), blo(v3))));
        p0 = fmaxf(p0, fmaxf(fmaxf(blo(v4), blo(v5)), fmaxf(blo(v6), blo(v7))));
        m1 = fmaxf(m1, fmaxf(fmaxf(bhi(v0), bhi(v1)), fmaxf(bhi(v2), bhi(v3))));
        p1 = fmaxf(p1, fmaxf(fmaxf(bhi(v4), bhi(v5)), fmaxf(bhi(v6), bhi(v7))));
    }
    for (; j + 2 <= re; j += 2) {
        unsigned v0 = Xb[(size_t)esrc[j] * 32 + lt], v1 = Xb[(size_t)esrc[j + 1] * 32 + lt];
        m0 = fmaxf(m0, blo(v0)); p0 = fmaxf(p0, blo(v1));
        m1 = fmaxf(m1, bhi(v0)); p1 = fmaxf(p1, bhi(v1));
    }
    if (j < re) {
        unsigned v = Xb[(size_t)esrc[j] * 32 + lt];
        m0 = fmaxf(m0, blo(v)); m1 = fmaxf(m1, bhi(v));
    }
    m0 = fmaxf(m0, p0);
    m1 = fmaxf(m1, p1);
    // empty node -> -inf -> 0xFF80 (handled in consumer); bfr exact on bf16-valued maxima
    Ab[(size_t)n * 32 + lt] = bfr(m0) | (bfr(m1) << 16);
}

// ---------------- GEMM: decode A (+prev-layer norm/relu), compute h, stats ----------------
__launch_bounds__(256)
__global__ void k_gemm(const unsigned* __restrict__ Ab, const unsigned* __restrict__ eaggk,
                       const float* __restrict__ ss, int apply,
                       const float* __restrict__ W, const float* __restrict__ b,
                       unsigned* __restrict__ Hb, float* __restrict__ stats) {
    __shared__ float Wl[FAN][D];    // 17.9 KB
    __shared__ float Ag[64][74];    // 18.9 KB
    __shared__ float ls[128];

    int tid = threadIdx.x;
    int n0 = blockIdx.x * 64;

    for (int i = tid; i < FAN * D; i += 256) Wl[i >> 6][i & 63] = W[i];
    for (int i = tid; i < 64 * 32; i += 256) {
        int r = i >> 5, c2 = i & 31;
        int n = n0 + r;
        unsigned wv = (n < NN) ? Ab[(size_t)n * 32 + c2] : 0xFF80FF80u;
        float a0 = blo(wv), a1 = bhi(wv);
        if (apply) {
            a0 = (a0 == NINF) ? 0.f : fmaxf(fmaf(a0, ss[2 * c2], ss[D + 2 * c2]), 0.f);
            a1 = (a1 == NINF) ? 0.f : fmaxf(fmaf(a1, ss[2 * c2 + 1], ss[D + 2 * c2 + 1]), 0.f);
        } else {
            a0 = (a0 == NINF) ? 0.f : a0;
            a1 = (a1 == NINF) ? 0.f : a1;
        }
        *(float2*)&Ag[r][2 * c2] = make_float2(a0, a1);
    }
    for (int i = tid; i < 64 * 8; i += 256) {
        int r = i >> 3, c = i & 7;
        int n = n0 + r;
        float v = 0.f;
        if (c < DE && n < NN) {
            unsigned u = eaggk[n * DE + c];
            v = (u == ENC_NEGINF) ? 0.f : dec(u);
        }
        Ag[r][64 + c] = v;
    }
    if (tid < 128) ls[tid] = 0.f;
    __syncthreads();

    int tr = tid >> 4, tc = tid & 15;
    int r0 = tr * 4, c0 = tc * 4;
    float acc[4][4];
    #pragma unroll
    for (int i = 0; i < 4; i++)
        #pragma unroll
        for (int jj = 0; jj < 4; jj++) acc[i][jj] = 0.f;

    for (int k = 0; k < FAN; k++) {
        float4 wv = *(const float4*)&Wl[k][c0];
        float a0 = Ag[r0 + 0][k];
        float a1 = Ag[r0 + 1][k];
        float a2 = Ag[r0 + 2][k];
        float a3 = Ag[r0 + 3][k];
        acc[0][0] = fmaf(a0, wv.x, acc[0][0]); acc[0][1] = fmaf(a0, wv.y, acc[0][1]);
        acc[0][2] = fmaf(a0, wv.z, acc[0][2]); acc[0][3] = fmaf(a0, wv.w, acc[0][3]);
        acc[1][0] = fmaf(a1, wv.x, acc[1][0]); acc[1][1] = fmaf(a1, wv.y, acc[1][1]);
        acc[1][2] = fmaf(a1, wv.z, acc[1][2]); acc[1][3] = fmaf(a1, wv.w, acc[1][3]);
        acc[2][0] = fmaf(a2, wv.x, acc[2][0]); acc[2][1] = fmaf(a2, wv.y, acc[2][1]);
        acc[2][2] = fmaf(a2, wv.z, acc[2][2]); acc[2][3] = fmaf(a2, wv.w, acc[2][3]);
        acc[3][0] = fmaf(a3, wv.x, acc[3][0]); acc[3][1] = fmaf(a3, wv.y, acc[3][1]);
        acc[3][2] = fmaf(a3, wv.z, acc[3][2]); acc[3][3] = fmaf(a3, wv.w, acc[3][3]);
    }

    float4 bb = *(const float4*)&b[c0];
    float cs[4] = {0.f, 0.f, 0.f, 0.f};
    float cq[4] = {0.f, 0.f, 0.f, 0.f};
    #pragma unroll
    for (int i = 0; i < 4; i++) {
        int n = n0 + r0 + i;
        if (n < NN) {
            float ox = acc[i][0] + bb.x, oy = acc[i][1] + bb.y;
            float oz = acc[i][2] + bb.z, ow = acc[i][3] + bb.w;
            uint2 pk = make_uint2(bfr(ox) | (bfr(oy) << 16), bfr(oz) | (bfr(ow) << 16));
            *(uint2*)&Hb[(size_t)n * 32 + (c0 >> 1)] = pk;
            cs[0] += ox; cs[1] += oy; cs[2] += oz; cs[3] += ow;
            cq[0] += ox * ox; cq[1] += oy * oy; cq[2] += oz * oz; cq[3] += ow * ow;
        }
    }
    #pragma unroll
    for (int jj = 0; jj < 4; jj++) {
        atomicAdd(&ls[c0 + jj], cs[jj]);
        atomicAdd(&ls[64 + c0 + jj], cq[jj]);
    }
    __syncthreads();
    if (tid < 128) atomicAdd(&stats[tid], ls[tid]);
}

__global__ void k_finalize_stats(const float* __restrict__ stats, const float* __restrict__ g,
                                 const float* __restrict__ beta, float* __restrict__ ss) {
    int j = threadIdx.x;  // 64 threads
    float mean = stats[j] * (1.0f / NN);
    float var = stats[64 + j] * (1.0f / NN) - mean * mean;
    float sc = rsqrtf(var + EPS) * g[j];
    ss[j] = sc;
    ss[64 + j] = beta[j] - mean * sc;
}

// graph offsets from sorted batch
__global__ void k_gptr(const int* __restrict__ batch, int* __restrict__ gptr) {
    int i = blockIdx.x * 256 + threadIdx.x;
    if (i >= NN) return;
    int b = batch[i];
    int prev = (i == 0) ? -1 : batch[i - 1];
    for (int g = prev + 1; g <= b; ++g) gptr[g] = i;
    if (i == NN - 1) {
        for (int g = b + 1; g <= NG; ++g) gptr[g] = NN;
    }
}

// pool(gather) + norm/relu + dot: half-wave per graph
__global__ void k_gfinal(const unsigned* __restrict__ Hb, const int* __restrict__ gptr,
                         const float* __restrict__ ss, const float* __restrict__ lw,
                         const float* __restrict__ lb, float* __restrict__ out) {
    int g = blockIdx.x * 8 + (threadIdx.x >> 5);
    int lt = threadIdx.x & 31;
    if (g >= NG) return;
    int rs = gptr[g], re = gptr[g + 1];
    float m0 = NINF, m1 = NINF, p0 = NINF, p1 = NINF;
    int n = rs;
    for (; n + 4 <= re; n += 4) {
        unsigned v0 = Hb[(size_t)(n + 0) * 32 + lt];
        unsigned v1 = Hb[(size_t)(n + 1) * 32 + lt];
        unsigned v2 = Hb[(size_t)(n + 2) * 32 + lt];
        unsigned v3 = Hb[(size_t)(n + 3) * 32 + lt];
        m0 = fmaxf(m0, fmaxf(blo(v0), blo(v1))); m1 = fmaxf(m1, fmaxf(bhi(v0), bhi(v1)));
        p0 = fmaxf(p0, fmaxf(blo(v2), blo(v3))); p1 = fmaxf(p1, fmaxf(bhi(v2), bhi(v3)));
    }
    for (; n < re; ++n) {
        unsigned v = Hb[(size_t)n * 32 + lt];
        m0 = fmaxf(m0, blo(v)); m1 = fmaxf(m1, bhi(v));
    }
    m0 = fmaxf(m0, p0);
    m1 = fmaxf(m1, p1);
    float a0 = (m0 == NINF) ? 0.f : fmaxf(fmaf(m0, ss[2 * lt], ss[D + 2 * lt]), 0.f);
    float a1 = (m1 == NINF) ? 0.f : fmaxf(fmaf(m1, ss[2 * lt + 1], ss[D + 2 * lt + 1]), 0.f);
    float p = fmaf(a0, lw[2 * lt], a1 * lw[2 * lt + 1]);
    #pragma unroll
    for (int off = 1; off < 32; off <<= 1) p += __shfl_xor(p, off);
    if (lt == 0) out[g] = p + lb[0];
}

extern "C" void kernel_launch(void* const* d_in, const int* in_sizes, int n_in,
                              void* d_out, int out_size, void* d_ws, size_t ws_size,
                              hipStream_t stream) {
    const float* x     = (const float*)d_in[0];
    const int*   ei    = (const int*)d_in[1];
    const float* ea    = (const float*)d_in[2];
    const int*   batch = (const int*)d_in[3];
    const float* Wp[3] = {(const float*)d_in[4],  (const float*)d_in[8],  (const float*)d_in[12]};
    const float* bp[3] = {(const float*)d_in[5],  (const float*)d_in[9],  (const float*)d_in[13]};
    const float* gp[3] = {(const float*)d_in[6],  (const float*)d_in[10], (const float*)d_in[14]};
    const float* tp[3] = {(const float*)d_in[7],  (const float*)d_in[11], (const float*)d_in[15]};
    const float* lw    = (const float*)d_in[16];
    const float* lb    = (const float*)d_in[17];
    float* out = (float*)d_out;

    const int* src = ei;
    const int* dst = ei + NE;

    // workspace layout (u32 words; fill targets 16B-aligned)
    unsigned* w = (unsigned*)d_ws;
    int*      rowptr = (int*)w;                    // 100004
    int*      counts = (int*)(w + 100004);         // 100004
    int*      esrc   = (int*)(w + 200008);         // 1600000
    unsigned* eaggk  = w + 1800008;                // 600000
    int*      bsum   = (int*)(w + 2400008);        // 256
    float*    stats  = (float*)(w + 2400264);      // 128
    float*    ss     = (float*)(w + 2400392);      // 128
    int*      gptr   = (int*)(w + 2400520);        // 1028
    int*      gcnt   = (int*)(w + 2401548);        // 212
    unsigned* gbuck  = w + 2401760;                // 196*10240 = 2007040
    unsigned* Xb0    = w + 4408800;                // 3200000
    unsigned* Hb1    = w + 7608800;                // 3200000
    unsigned* Hb2    = w + 10808800;               // 3200000  (end: 56.0 MB)

    const int NB = (NN + SCAN_BS - 1) / SCAN_BS;   // 196

    // --- CSR build: hist/scan + write-coalesced 2-pass binning ---
    k_fill_u32x4<<<(25001 + 255) / 256, 256, 0, stream>>>((uint4*)counts, 0u, 25001);
    k_fill_u32x4<<<1, 53, 0, stream>>>((uint4*)gcnt, 0u, 53);
    k_hist<<<NE / 256, 256, 0, stream>>>(dst, counts);
    k_binA<<<NBUK, 256, 0, stream>>>(src, dst, gcnt, gbuck);
    k_scan1<<<NB, SCAN_BS, 0, stream>>>(counts, rowptr, bsum);
    k_scan2<<<1, 256, 0, stream>>>(bsum, NB);
    k_scan3<<<(NN + 1 + 255) / 256, 256, 0, stream>>>(rowptr, bsum);
    k_binB<<<NBUK, 256, 0, stream>>>(gbuck, gcnt, rowptr, esrc);

    // --- edge_attr seg-max + bf16 cast + graph offsets ---
    k_fill_u32x4<<<(150000 + 255) / 256, 256, 0, stream>>>((uint4*)eaggk, ENC_NEGINF, 150000);
    k_scatter_e<<<NE / 32, 256, 0, stream>>>(ea, dst, eaggk);
    k_cast<<<(NN * 16 + 255) / 256, 256, 0, stream>>>((const float4*)x, (uint2*)Xb0, NN * 16);
    k_gptr<<<(NN + 255) / 256, 256, 0, stream>>>(batch, gptr);

    // --- 3 layers: agg (raw bf16 maxima) -> gemm (decode + fused prev norm/relu) ---
    // buffers: l0: Xb0 -> A=Hb2 -> H=Hb1 ; l1: Hb1 -> A=Xb0 -> H=Hb2 ; l2: Hb2 -> A=Hb1 -> H=Xb0
    const unsigned* ain[3] = {Xb0, Hb1, Hb2};
    unsigned* abuf[3] = {Hb2, Xb0, Hb1};
    unsigned* hbuf[3] = {Hb1, Hb2, Xb0};
    for (int l = 0; l < 3; ++l) {
        k_agg<<<NN / 8, 256, 0, stream>>>(ain[l], rowptr, esrc, abuf[l]);
        k_fill_u32x4<<<1, 32, 0, stream>>>((uint4*)stats, 0u, 32);
        k_gemm<<<(NN + 63) / 64, 256, 0, stream>>>(abuf[l], eaggk, ss, l > 0 ? 1 : 0,
                                                   Wp[l], bp[l], hbuf[l], stats);
        k_finalize_stats<<<1, 64, 0, stream>>>(stats, gp[l], tp[l], ss);
    }

    // --- pooled gather + final norm/relu/dot ---
    k_gfinal<<<NG / 8, 256, 0, stream>>>(Xb0, gptr, ss, lw, lb, out);
}